// Round 7
// baseline (204.592 us; speedup 1.0000x reference)
//
#include <hip/hip_runtime.h>
#include <math.h>

#define B_ 4
#define S_ 2048
#define D_ 512
#define H_ 8
#define HD_ 64
#define RL_ 64
#define LN_EPS 1e-5f
#define SLOPE 0.01f
#define LOG2E 1.4426950408889634f

typedef __attribute__((ext_vector_type(8))) __bf16 bf16x8;
typedef __attribute__((ext_vector_type(4))) float f32x4;
typedef __attribute__((ext_vector_type(16))) float f32x16;

__device__ __forceinline__ float leaky(float x) { return x >= 0.f ? x : SLOPE * x; }

// float -> bf16 (RNE)
__device__ __forceinline__ ushort f2bf(float f) {
    union { float f; unsigned u; } v; v.f = f;
    unsigned r = v.u + 0x7fffu + ((v.u >> 16) & 1u);
    return (ushort)(r >> 16);
}
// hardware packed f32x2 -> bf16x2 (lo = a, hi = b)
__device__ __forceinline__ unsigned cvtpk(float a, float b) {
    unsigned r;
    asm("v_cvt_pk_bf16_f32 %0, %1, %2" : "=v"(r) : "v"(a), "v"(b));
    return r;
}

__device__ __forceinline__ void g2lds16(const void* g, void* l) {
    __builtin_amdgcn_global_load_lds(
        (const __attribute__((address_space(1))) void*)(uintptr_t)g,
        (__attribute__((address_space(3))) void*)(uintptr_t)l, 16, 0, 0);
}

// exchange 32-lane halves between x and y
__device__ __forceinline__ void plane32swap(unsigned &x, unsigned &y) {
    asm volatile("v_permlane32_swap_b32 %0, %1" : "+v"(x), "+v"(y));
}

// ---------------------------------------------------------------------------
// prep (merged): grid 4752
// ---------------------------------------------------------------------------
__global__ __launch_bounds__(256) void prep(
    const float* __restrict__ h, const float* __restrict__ rh,
    const float* __restrict__ Wr, const float* __restrict__ Wf,
    const float* __restrict__ Wrs, const float* __restrict__ Wrt,
    ushort* __restrict__ hb, ushort* __restrict__ rhb,
    ushort* __restrict__ WrT, ushort* __restrict__ WfT,
    ushort* __restrict__ WrsT, ushort* __restrict__ WrtT)
{
    const int bx = blockIdx.x, tid = threadIdx.x;
    if (bx < 4608) {
        const float* in = (bx < 4096) ? h : rh;
        ushort* o = (bx < 4096) ? hb : rhb;
        const int i = (bx < 4096 ? bx : bx - 4096) * 256 + tid;
        const float4 v = ((const float4*)in)[i];
        ushort4 u; u.x = f2bf(v.x); u.y = f2bf(v.y); u.z = f2bf(v.z); u.w = f2bf(v.w);
        ((ushort4*)o)[i] = u;
        return;
    }
    __shared__ float TS[64][65];
    int t = bx - 4608;
    const float* in; ushort* out; int K, tk, tn;
    if (t < 64)       { in = Wr;  out = WrT;  K = 512; tk = t & 7; tn = t >> 3; }
    else if (t < 128) { in = Wf;  out = WfT;  K = 512; t -= 64; tk = t & 7; tn = t >> 3; }
    else if (t < 136) { in = Wrs; out = WrsT; K = 64;  tk = 0; tn = t - 128; }
    else              { in = Wrt; out = WrtT; K = 64;  tk = 0; tn = t - 136; }
    const int k0 = tk * 64, n0 = tn * 64;
    const int r = tid >> 4, c4 = (tid & 15) * 4;
    #pragma unroll
    for (int p = 0; p < 4; ++p) {
        const int row = r + 16 * p;
        const float4 v = *(const float4*)(in + (size_t)(k0 + row) * 512 + n0 + c4);
        TS[row][c4] = v.x; TS[row][c4 + 1] = v.y;
        TS[row][c4 + 2] = v.z; TS[row][c4 + 3] = v.w;
    }
    __syncthreads();
    #pragma unroll
    for (int p = 0; p < 4; ++p) {
        const int nn = r + 16 * p;
        ushort4 o;
        o.x = f2bf(TS[c4 + 0][nn]); o.y = f2bf(TS[c4 + 1][nn]);
        o.z = f2bf(TS[c4 + 2][nn]); o.w = f2bf(TS[c4 + 3][nn]);
        *(ushort4*)(out + (size_t)(n0 + nn) * K + k0 + c4) = o;
    }
}

// ---------------------------------------------------------------------------
// proj (fused): grid (128,4,3). z=0: fr-projection (K=512) -> frT bf16 + sr;
// z=1: rk (K=64, xLOG2E); z=2: rq (K=64).
// frT t-columns written PERMUTED within 16-blocks (groups [0,3,1,2]) so the
// attn PV B-frag k-slots line up with permlane32_swap P construction.
// ---------------------------------------------------------------------------
__global__ __launch_bounds__(256) void proj(
    const ushort* __restrict__ hb, const ushort* __restrict__ rhb,
    const ushort* __restrict__ WrT, const ushort* __restrict__ WrsT,
    const ushort* __restrict__ WrtT,
    ushort* __restrict__ frT, ushort* __restrict__ rkw, ushort* __restrict__ rqw,
    float* __restrict__ sred, const float* __restrict__ ar)
{
    __shared__ ushort As[2][64 * 32];
    __shared__ ushort Bs[2][128 * 32];

    const int tid = threadIdx.x;
    const int lane = tid & 63, w = tid >> 6;
    const int ln = lane & 15, quad = lane >> 4;
    const int wm = w >> 1, wn = w & 1;
    const int m0 = blockIdx.x * 64, n0 = blockIdx.y * 128;
    const int z = blockIdx.z;

    const ushort* A; const ushort* wt; ushort* co; float scl; int K;
    if (z == 0)      { A = hb;  wt = WrT;  co = frT; scl = LOG2E; K = 512; }
    else if (z == 1) { A = rhb; wt = WrsT; co = rkw; scl = LOG2E; K = 64; }
    else             { A = rhb; wt = WrtT; co = rqw; scl = 1.0f;  K = 64; }

    const int srA = tid >> 2;
    const int lchA = ((lane & 3) - (srA >> 1)) & 3;
    const ushort* AgB = A + (size_t)(m0 + srA) * K + lchA * 8;
    const int srB = w * 32 + (lane >> 2);
    const int lchB = ((lane & 3) - (srB >> 1)) & 3;
    const ushort* BgB0 = wt + (size_t)(n0 + srB) * K + lchB * 8;
    const ushort* BgB1 = BgB0 + (size_t)16 * K;
    const int aoff = tid * 8;
    const int boff = srB * 32 + (lane & 3) * 8;
    const int pc = (quad + (ln >> 1)) & 3;

    g2lds16(AgB, &As[0][aoff]);
    g2lds16(BgB0, &Bs[0][boff]);
    g2lds16(BgB1, &Bs[0][boff + 512]);

    f32x4 acc[2][4] = {};
    int buf = 0;
    for (int k0 = 0; k0 < K; k0 += 32) {
        __syncthreads();
        if (k0 + 32 < K) {
            g2lds16(AgB + k0 + 32, &As[buf ^ 1][aoff]);
            g2lds16(BgB0 + k0 + 32, &Bs[buf ^ 1][boff]);
            g2lds16(BgB1 + k0 + 32, &Bs[buf ^ 1][boff + 512]);
        }
        bf16x8 af[2], bfr[4];
        #pragma unroll
        for (int mi = 0; mi < 2; ++mi)
            af[mi] = *(const bf16x8*)&As[buf][(wm * 32 + mi * 16 + ln) * 32 + pc * 8];
        #pragma unroll
        for (int ni = 0; ni < 4; ++ni)
            bfr[ni] = *(const bf16x8*)&Bs[buf][(wn * 64 + ni * 16 + ln) * 32 + pc * 8];
        #pragma unroll
        for (int mi = 0; mi < 2; ++mi)
            #pragma unroll
            for (int ni = 0; ni < 4; ++ni)
                acc[mi][ni] = __builtin_amdgcn_mfma_f32_16x16x32_bf16(
                    af[mi], bfr[ni], acc[mi][ni], 0, 0, 0);
        buf ^= 1;
    }

    const int head = blockIdx.y * 2 + wn;
    const int b = m0 >> 11;
    const size_t bh = (size_t)b * H_ + head;
    if (z == 0) {
        #pragma unroll
        for (int mi = 0; mi < 2; ++mi) {
            const int s = (m0 & (S_ - 1)) + wm * 32 + mi * 16 + quad * 4;
            // t-permutation: group (s>>2)&3 == quad -> slot [0,2,3,1]
            const int sp = (s & ~15) | ((((0x1320u >> (quad * 4)) & 0xFu)) << 2);
            #pragma unroll
            for (int ni = 0; ni < 4; ++ni) {
                const int d = ni * 16 + ln;
                ushort4 o;
                o.x = f2bf(acc[mi][ni][0]); o.y = f2bf(acc[mi][ni][1]);
                o.z = f2bf(acc[mi][ni][2]); o.w = f2bf(acc[mi][ni][3]);
                *(ushort4*)(co + (bh * 64 + d) * S_ + sp) = o;
            }
        }
        float a4[4];
        #pragma unroll
        for (int ni = 0; ni < 4; ++ni) a4[ni] = ar[ni * 16 + ln];
        #pragma unroll
        for (int mi = 0; mi < 2; ++mi) {
            const int s = (m0 & (S_ - 1)) + wm * 32 + mi * 16 + quad * 4;
            #pragma unroll
            for (int r = 0; r < 4; ++r) {
                float v = 0.f;
                #pragma unroll
                for (int ni = 0; ni < 4; ++ni)
                    v += leaky(acc[mi][ni][r]) * a4[ni];
                #pragma unroll
                for (int off = 8; off; off >>= 1) v += __shfl_xor(v, off, 16);
                if (ln == 0) sred[bh * S_ + s + r] = v * scl;
            }
        }
    } else {
        #pragma unroll
        for (int mi = 0; mi < 2; ++mi) {
            const int s = (m0 & (S_ - 1)) + wm * 32 + mi * 16 + quad * 4;
            #pragma unroll
            for (int ni = 0; ni < 4; ++ni) {
                const int d = ni * 16 + ln;
                #pragma unroll
                for (int r = 0; r < 4; ++r)
                    co[(bh * S_ + s + r) * 64 + d] = f2bf(acc[mi][ni][r] * scl);
            }
        }
    }
}

// ---------------------------------------------------------------------------
// Flash attention, 32x32x16 bf16 MFMA, swapped QK^T, in-register P.
// Round 7: t-SPLIT waves. 256 thr = 4 waves = (qg 0..1) x (th 0..1); block
// covers 128 q; each wave: 64 q (qb = q0+64qg), t-subtile th (32 t of each
// 64-t tile; PV chunks ts = 2th+c). Grid 512 -> 2 blocks/CU -> 8 waves/CU
// (R2's TLP at R6's reduced LDS traffic). Dataflow identical to R6 per
// 16-t chunk (proj t-permutation + permlane32_swap construction verified).
// cvt_pk_bf16_f32 replaces software f2bf packing in softmax (T12 primitive).
// Epilogue: partner waves exchange partial ctx (non-owned d-half) + lsum via
// the freed 32 KB staging LDS, each wave stores its own d-half.
// ---------------------------------------------------------------------------
#define WAITV(N) asm volatile("s_waitcnt vmcnt(" #N ")" ::: "memory")
#define BARR()   __builtin_amdgcn_s_barrier()

__global__ __launch_bounds__(256, 1) void attn_mfma(
    const ushort* __restrict__ frT, const ushort* __restrict__ rk,
    const ushort* __restrict__ rq, const float* __restrict__ sr,
    ushort* __restrict__ hsa)
{
    __shared__ ushort SMEM[16384];     // 32 KB: RQ[2] @0, FT[2] @8192 (ushorts)
    __shared__ float  LS[4][2][64];    // lsum exchange, 2 KB
    ushort* RQp = SMEM;
    ushort* FTp = SMEM + 8192;

    const int tid = threadIdx.x;
    const int w = tid >> 6;            // wave 0..3
    const int qg = w >> 1;             // q-group
    const int th = w & 1;              // t-half
    const int lane = tid & 63;
    const int lq = lane & 31;
    const int hi = lane >> 5;

    // bijective XCD swizzle over 512 blocks
    const int flat = blockIdx.x + 16 * (blockIdx.y + 8 * blockIdx.z);
    const int wid = (flat & 7) * 64 + (flat >> 3);
    const int q0 = (wid & 15) * 128;
    const int h = (wid >> 4) & 7;
    const int b = wid >> 7;
    const size_t bh = (size_t)b * H_ + h;
    const int qb = q0 + 64 * qg;       // wave's 64 q

    // rk B-frags: col q = qb + 32*qt + lq, k = ks*16 + hi*8
    bf16x8 bq[2][4];
    #pragma unroll
    for (int qt = 0; qt < 2; ++qt) {
        const ushort* p = rk + ((bh * S_ + qb + 32 * qt + lq) << 6) + hi * 8;
        #pragma unroll
        for (int ks = 0; ks < 4; ++ks)
            bq[qt][ks] = *(const bf16x8*)(p + ks * 16);
    }

    const ushort* rq_g = rq + (bh * S_ << 6);
    const ushort* ft_g = frT + (size_t)bh * 64 * S_;
    const float* srp = sr + bh * S_;

    // staging (256 thr): rows rr = 32j + (tid>>3), granule pg = tid&7;
    // 2 rows x 2 arrays = 4 g2lds16/thread. Per-wave dest is lane-linear.
    const int srow = tid >> 3;         // 0..31
    const int pg = tid & 7;
    const int oS = (pg - (srow & 7)) & 7;

    #define STAGE(BUF, t0)                                                    \
        { _Pragma("unroll")                                                   \
          for (int j = 0; j < 2; ++j) {                                       \
            const int rr = 32 * j + srow;                                     \
            g2lds16(rq_g + ((size_t)((t0) + rr) << 6) + oS * 8,               \
                    RQp + (BUF) * 4096 + rr * 64 + pg * 8);                   \
            g2lds16(ft_g + (size_t)rr * S_ + (t0) + oS * 8,                   \
                    FTp + (BUF) * 4096 + rr * 64 + pg * 8);                   \
          } }

    f32x16 ctx[2][2] = {};
    float lsum[2] = {0.f, 0.f};

    #define COMPUTE(BI, TC)                                                    \
    {                                                                          \
        bf16x8 af[4];                                                          \
        _Pragma("unroll")                                                      \
        for (int ks = 0; ks < 4; ++ks)                                         \
            af[ks] = *(const bf16x8*)(RQp + (BI) * 4096 + (th * 32 + lq) * 64  \
                       + ((2 * ks + hi + (lq & 7)) & 7) * 8);                  \
        f32x16 s0 = {}; f32x16 s1 = {};                                        \
        _Pragma("unroll")                                                      \
        for (int ks = 0; ks < 4; ++ks) {                                       \
            s0 = __builtin_amdgcn_mfma_f32_32x32x16_bf16(af[ks], bq[0][ks], s0, 0, 0, 0); \
            s1 = __builtin_amdgcn_mfma_f32_32x32x16_bf16(af[ks], bq[1][ks], s1, 0, 0, 0); \
        }                                                                      \
        float sva[16];                                                         \
        _Pragma("unroll")                                                      \
        for (int jj = 0; jj < 4; ++jj) {                                       \
            const float4 v = *(const float4*)(srp + (TC) + th * 32 + jj * 8 + hi * 4); \
            sva[jj * 4 + 0] = v.x; sva[jj * 4 + 1] = v.y;                      \
            sva[jj * 4 + 2] = v.z; sva[jj * 4 + 3] = v.w;                      \
        }                                                                      \
        uint4 paw[2][2];                                                       \
        _Pragma("unroll")                                                      \
        for (int qt = 0; qt < 2; ++qt) {                                       \
            float p[16];                                                       \
            _Pragma("unroll")                                                  \
            for (int r = 0; r < 16; ++r)                                       \
                p[r] = __builtin_amdgcn_exp2f((qt ? s1[r] : s0[r]) + sva[r]);  \
            float ls = 0.f;                                                    \
            _Pragma("unroll")                                                  \
            for (int r = 0; r < 16; ++r) ls += p[r];                           \
            lsum[qt] += ls;                                                    \
            _Pragma("unroll")                                                  \
            for (int c = 0; c < 2; ++c) {                                      \
                const int e = 8 * c;                                           \
                unsigned c01 = cvtpk(p[e + 0], p[e + 1]);                      \
                unsigned c23 = cvtpk(p[e + 2], p[e + 3]);                      \
                unsigned c45 = cvtpk(p[e + 4], p[e + 5]);                      \
                unsigned c67 = cvtpk(p[e + 6], p[e + 7]);                      \
                plane32swap(c45, c67);                                         \
                paw[qt][c] = make_uint4(c01, c23, c67, c45);                   \
            }                                                                  \
        }                                                                      \
        _Pragma("unroll")                                                      \
        for (int c = 0; c < 2; ++c) {                                          \
            _Pragma("unroll")                                                  \
            for (int dt = 0; dt < 2; ++dt) {                                   \
                const bf16x8 fv = *(const bf16x8*)(FTp + (BI) * 4096           \
                    + (dt * 32 + lq) * 64                                      \
                    + ((4 * th + 2 * c + hi + (lq & 7)) & 7) * 8);             \
                ctx[0][dt] = __builtin_amdgcn_mfma_f32_32x32x16_bf16(          \
                    __builtin_bit_cast(bf16x8, paw[0][c]), fv, ctx[0][dt], 0, 0, 0); \
                ctx[1][dt] = __builtin_amdgcn_mfma_f32_32x32x16_bf16(          \
                    __builtin_bit_cast(bf16x8, paw[1][c]), fv, ctx[1][dt], 0, 0, 0); \
            }                                                                  \
        }                                                                      \
    }

    // prologue
    STAGE(0, 0)
    // 32 tiles: 15 x 2 + tail 2
    for (int it = 0; it < 15; ++it) {
        const int t0 = it * 128;
        WAITV(0); BARR();
        STAGE(1, t0 + 64)
        COMPUTE(0, t0)
        WAITV(0); BARR();
        STAGE(0, t0 + 128)
        COMPUTE(1, t0 + 64)
    }
    WAITV(0); BARR();
    STAGE(1, 1984)
    COMPUTE(0, 1920)
    WAITV(0); BARR();
    COMPUTE(1, 1984)

    // ---- epilogue: combine t-split partials across partner waves ----
    BARR();   // all compute reads of SMEM done; safe to reuse as CX
    float* CX = (float*)SMEM;                 // 8192 floats = 32 KB
    float* CXw = CX + w * 2048;
    // write my partial for the NON-owned d-half (dt = 1-th), conflict-free
    #pragma unroll
    for (int qt = 0; qt < 2; ++qt)
        #pragma unroll
        for (int r = 0; r < 16; ++r)
            CXw[(qt * 16 + r) * 64 + lane] = ctx[qt][1 - th][r];
    LS[w][0][lane] = lsum[0];
    LS[w][1][lane] = lsum[1];
    BARR();
    const float* CXp = CX + (w ^ 1) * 2048;   // partner's written region
    #pragma unroll
    for (int qt = 0; qt < 2; ++qt) {
        float lt = lsum[qt] + LS[w ^ 1][qt][lane];
        const float l = lt + __shfl_xor(lt, 32, 64);
        const float inv = 1.f / l;
        #pragma unroll
        for (int r = 0; r < 16; ++r) {
            const float cv = ctx[qt][th][r] + CXp[(qt * 16 + r) * 64 + lane];
            const int rho = (r & 3) + 8 * (r >> 2) + 4 * hi;
            const float fi = __shfl(inv, rho, 64);
            const int q = qb + 32 * qt + rho;
            hsa[(size_t)(b * S_ + q) * D_ + h * 64 + th * 32 + lq] = f2bf(cv * fi);
        }
    }
}

// ---------------------------------------------------------------------------
// final projection GEMM (fp32 out), double-buffered
// ---------------------------------------------------------------------------
__global__ __launch_bounds__(256) void gemm_out(
    const ushort* __restrict__ A, const ushort* __restrict__ WT,
    float* __restrict__ C)
{
    __shared__ ushort As[2][64 * 32];
    __shared__ ushort Bs[2][128 * 32];

    const int tid = threadIdx.x;
    const int lane = tid & 63, w = tid >> 6;
    const int ln = lane & 15, quad = lane >> 4;
    const int wm = w >> 1, wn = w & 1;
    const int m0 = blockIdx.x * 64, n0 = blockIdx.y * 128;
    const int K = 512;

    const int srA = tid >> 2;
    const int lchA = ((lane & 3) - (srA >> 1)) & 3;
    const ushort* AgB = A + (size_t)(m0 + srA) * K + lchA * 8;
    const int srB = w * 32 + (lane >> 2);
    const int lchB = ((lane & 3) - (srB >> 1)) & 3;
    const ushort* BgB0 = WT + (size_t)(n0 + srB) * K + lchB * 8;
    const ushort* BgB1 = BgB0 + (size_t)16 * K;
    const int aoff = tid * 8;
    const int boff = srB * 32 + (lane & 3) * 8;
    const int pc = (quad + (ln >> 1)) & 3;

    g2lds16(AgB, &As[0][aoff]);
    g2lds16(BgB0, &Bs[0][boff]);
    g2lds16(BgB1, &Bs[0][boff + 512]);

    f32x4 acc[2][4] = {};
    int buf = 0;
    for (int k0 = 0; k0 < K; k0 += 32) {
        __syncthreads();
        if (k0 + 32 < K) {
            g2lds16(AgB + k0 + 32, &As[buf ^ 1][aoff]);
            g2lds16(BgB0 + k0 + 32, &Bs[buf ^ 1][boff]);
            g2lds16(BgB1 + k0 + 32, &Bs[buf ^ 1][boff + 512]);
        }
        bf16x8 af[2], bfr[4];
        #pragma unroll
        for (int mi = 0; mi < 2; ++mi)
            af[mi] = *(const bf16x8*)&As[buf][(wm * 32 + mi * 16 + ln) * 32 + pc * 8];
        #pragma unroll
        for (int ni = 0; ni < 4; ++ni)
            bfr[ni] = *(const bf16x8*)&Bs[buf][(wn * 64 + ni * 16 + ln) * 32 + pc * 8];
        #pragma unroll
        for (int mi = 0; mi < 2; ++mi)
            #pragma unroll
            for (int ni = 0; ni < 4; ++ni)
                acc[mi][ni] = __builtin_amdgcn_mfma_f32_16x16x32_bf16(
                    af[mi], bfr[ni], acc[mi][ni], 0, 0, 0);
        buf ^= 1;
    }

    #pragma unroll
    for (int mi = 0; mi < 2; ++mi) {
        const int row = m0 + wm * 32 + mi * 16 + quad * 4;
        #pragma unroll
        for (int ni = 0; ni < 4; ++ni) {
            const int col = n0 + wn * 64 + ni * 16 + ln;
            #pragma unroll
            for (int r = 0; r < 4; ++r)
                C[(size_t)(row + r) * 512 + col] = acc[mi][ni][r];
        }
    }
}

// ---------------------------------------------------------------------------
// LayerNorm(h + fh) * g + b
// ---------------------------------------------------------------------------
__global__ __launch_bounds__(256) void ln_kernel(
    const float* __restrict__ h, const float* __restrict__ fh,
    const float* __restrict__ g, const float* __restrict__ bb,
    float* __restrict__ out)
{
    const int row = blockIdx.x, tid = threadIdx.x;
    const float* hp = h + (size_t)row * 512;
    const float* fp = fh + (size_t)row * 512;
    const float x0 = hp[tid] + fp[tid];
    const float x1 = hp[tid + 256] + fp[tid + 256];
    __shared__ float red[4];

    float s = x0 + x1;
    #pragma unroll
    for (int off = 32; off; off >>= 1) s += __shfl_xor(s, off, 64);
    if ((tid & 63) == 0) red[tid >> 6] = s;
    __syncthreads();
    const float mu = (red[0] + red[1] + red[2] + red[3]) * (1.f / 512.f);

    const float d0 = x0 - mu, d1 = x1 - mu;
    float v = d0 * d0 + d1 * d1;
    #pragma unroll
    for (int off = 32; off; off >>= 1) v += __shfl_xor(v, off, 64);
    __syncthreads();
    if ((tid & 63) == 0) red[tid >> 6] = v;
    __syncthreads();
    const float var = (red[0] + red[1] + red[2] + red[3]) * (1.f / 512.f);
    const float inv = rsqrtf(var + LN_EPS);

    out[(size_t)row * 512 + tid] = d0 * inv * g[tid] + bb[tid];
    out[(size_t)row * 512 + tid + 256] = d1 * inv * g[tid + 256] + bb[tid + 256];
}

// ---------------------------------------------------------------------------
extern "C" void kernel_launch(void* const* d_in, const int* in_sizes, int n_in,
                              void* d_out, int out_size, void* d_ws, size_t ws_size,
                              hipStream_t stream)
{
    const float* h   = (const float*)d_in[0];
    const float* rh  = (const float*)d_in[1];
    // d_in[2] = Wl, d_in[4] = al : unused — sl cancels in softmax
    const float* Wr  = (const float*)d_in[3];
    const float* ar  = (const float*)d_in[5];
    const float* Wrs = (const float*)d_in[6];
    const float* Wrt = (const float*)d_in[7];
    const float* Wf  = (const float*)d_in[8];
    const float* lng = (const float*)d_in[9];
    const float* lnb = (const float*)d_in[10];
    float* out = (float*)d_out;
    char* wsb  = (char*)d_ws;

    const size_t MB = (size_t)1 << 20;
    ushort* hb   = (ushort*)(wsb);               //  8 MB
    ushort* rhb  = (ushort*)(wsb + 8 * MB);      //  1 MB
    ushort* WrT  = (ushort*)(wsb + 9 * MB);      // .5 MB
    ushort* WfT  = (ushort*)(wsb + 9 * MB + 512 * 1024);
    ushort* WrsT = (ushort*)(wsb + 10 * MB);     // 64 KB
    ushort* WrtT = (ushort*)(wsb + 10 * MB + 64 * 1024);
    ushort* frT  = (ushort*)(wsb + 11 * MB);     //  8 MB  [B,H,64,S] (t-permuted)
    ushort* rkw  = (ushort*)(wsb + 19 * MB);     //  8 MB  [B,H,S,64]
    ushort* rqw  = (ushort*)(wsb + 27 * MB);     //  8 MB  [B,H,S,64]
    float*  sr   = (float*) (wsb + 35 * MB);     // .25MB  [B,H,S]
    ushort* hsab = (ushort*)(wsb + 36 * MB);     //  8 MB  [B,S,512] bf16
    float*  fh   = (float*) (wsb + 44 * MB);     // 16 MB  [B,S,512] f32

    dim3 blk(256);
    prep<<<dim3(4752), blk, 0, stream>>>(h, rh, Wr, Wf, Wrs, Wrt,
                                         hb, rhb, WrT, WfT, WrsT, WrtT);
    proj<<<dim3(128, 4, 3), blk, 0, stream>>>(hb, rhb, WrT, WrsT, WrtT,
                                              frT, rkw, rqw, sr, ar);
    // attention: 4 waves (2 q-groups x 2 t-halves) per 256-thread block
    attn_mfma<<<dim3(S_ / 128, H_, B_), blk, 0, stream>>>(frT, rkw, rqw, sr, hsab);
    gemm_out<<<dim3(128, 4), blk, 0, stream>>>(hsab, WfT, fh);
    ln_kernel<<<dim3(B_ * S_), blk, 0, stream>>>(h, fh, lng, lnb, out);
}

// Round 8
// 174.273 us; speedup vs baseline: 1.1740x; 1.1740x over previous
//
#include <hip/hip_runtime.h>
#include <math.h>

#define B_ 4
#define S_ 2048
#define D_ 512
#define H_ 8
#define HD_ 64
#define RL_ 64
#define LN_EPS 1e-5f
#define SLOPE 0.01f
#define LOG2E 1.4426950408889634f

typedef __attribute__((ext_vector_type(8))) __bf16 bf16x8;
typedef __attribute__((ext_vector_type(4))) float f32x4;
typedef __attribute__((ext_vector_type(16))) float f32x16;

__device__ __forceinline__ float leaky(float x) { return x >= 0.f ? x : SLOPE * x; }

// float -> bf16 (RNE)
__device__ __forceinline__ ushort f2bf(float f) {
    union { float f; unsigned u; } v; v.f = f;
    unsigned r = v.u + 0x7fffu + ((v.u >> 16) & 1u);
    return (ushort)(r >> 16);
}
// hardware packed f32x2 -> bf16x2 (lo = a, hi = b)
__device__ __forceinline__ unsigned cvtpk(float a, float b) {
    unsigned r;
    asm("v_cvt_pk_bf16_f32 %0, %1, %2" : "=v"(r) : "v"(a), "v"(b));
    return r;
}

__device__ __forceinline__ void g2lds16(const void* g, void* l) {
    __builtin_amdgcn_global_load_lds(
        (const __attribute__((address_space(1))) void*)(uintptr_t)g,
        (__attribute__((address_space(3))) void*)(uintptr_t)l, 16, 0, 0);
}

// exchange 32-lane halves between x and y
__device__ __forceinline__ void plane32swap(unsigned &x, unsigned &y) {
    asm volatile("v_permlane32_swap_b32 %0, %1" : "+v"(x), "+v"(y));
}

// ---------------------------------------------------------------------------
// prep (merged): grid 4752
// ---------------------------------------------------------------------------
__global__ __launch_bounds__(256) void prep(
    const float* __restrict__ h, const float* __restrict__ rh,
    const float* __restrict__ Wr, const float* __restrict__ Wf,
    const float* __restrict__ Wrs, const float* __restrict__ Wrt,
    ushort* __restrict__ hb, ushort* __restrict__ rhb,
    ushort* __restrict__ WrT, ushort* __restrict__ WfT,
    ushort* __restrict__ WrsT, ushort* __restrict__ WrtT)
{
    const int bx = blockIdx.x, tid = threadIdx.x;
    if (bx < 4608) {
        const float* in = (bx < 4096) ? h : rh;
        ushort* o = (bx < 4096) ? hb : rhb;
        const int i = (bx < 4096 ? bx : bx - 4096) * 256 + tid;
        const float4 v = ((const float4*)in)[i];
        ushort4 u; u.x = f2bf(v.x); u.y = f2bf(v.y); u.z = f2bf(v.z); u.w = f2bf(v.w);
        ((ushort4*)o)[i] = u;
        return;
    }
    __shared__ float TS[64][65];
    int t = bx - 4608;
    const float* in; ushort* out; int K, tk, tn;
    if (t < 64)       { in = Wr;  out = WrT;  K = 512; tk = t & 7; tn = t >> 3; }
    else if (t < 128) { in = Wf;  out = WfT;  K = 512; t -= 64; tk = t & 7; tn = t >> 3; }
    else if (t < 136) { in = Wrs; out = WrsT; K = 64;  tk = 0; tn = t - 128; }
    else              { in = Wrt; out = WrtT; K = 64;  tk = 0; tn = t - 136; }
    const int k0 = tk * 64, n0 = tn * 64;
    const int r = tid >> 4, c4 = (tid & 15) * 4;
    #pragma unroll
    for (int p = 0; p < 4; ++p) {
        const int row = r + 16 * p;
        const float4 v = *(const float4*)(in + (size_t)(k0 + row) * 512 + n0 + c4);
        TS[row][c4] = v.x; TS[row][c4 + 1] = v.y;
        TS[row][c4 + 2] = v.z; TS[row][c4 + 3] = v.w;
    }
    __syncthreads();
    #pragma unroll
    for (int p = 0; p < 4; ++p) {
        const int nn = r + 16 * p;
        ushort4 o;
        o.x = f2bf(TS[c4 + 0][nn]); o.y = f2bf(TS[c4 + 1][nn]);
        o.z = f2bf(TS[c4 + 2][nn]); o.w = f2bf(TS[c4 + 3][nn]);
        *(ushort4*)(out + (size_t)(n0 + nn) * K + k0 + c4) = o;
    }
}

// ---------------------------------------------------------------------------
// proj (fused): grid (128,4,3). z=0: fr-projection (K=512) -> frT bf16 + sr;
// z=1: rk (K=64, xLOG2E); z=2: rq (K=64).
// frT t-columns written PERMUTED within 16-blocks (groups [0,3,1,2]) so the
// attn PV B-frag k-slots line up with permlane32_swap P construction.
// ---------------------------------------------------------------------------
__global__ __launch_bounds__(256) void proj(
    const ushort* __restrict__ hb, const ushort* __restrict__ rhb,
    const ushort* __restrict__ WrT, const ushort* __restrict__ WrsT,
    const ushort* __restrict__ WrtT,
    ushort* __restrict__ frT, ushort* __restrict__ rkw, ushort* __restrict__ rqw,
    float* __restrict__ sred, const float* __restrict__ ar)
{
    __shared__ ushort As[2][64 * 32];
    __shared__ ushort Bs[2][128 * 32];

    const int tid = threadIdx.x;
    const int lane = tid & 63, w = tid >> 6;
    const int ln = lane & 15, quad = lane >> 4;
    const int wm = w >> 1, wn = w & 1;
    const int m0 = blockIdx.x * 64, n0 = blockIdx.y * 128;
    const int z = blockIdx.z;

    const ushort* A; const ushort* wt; ushort* co; float scl; int K;
    if (z == 0)      { A = hb;  wt = WrT;  co = frT; scl = LOG2E; K = 512; }
    else if (z == 1) { A = rhb; wt = WrsT; co = rkw; scl = LOG2E; K = 64; }
    else             { A = rhb; wt = WrtT; co = rqw; scl = 1.0f;  K = 64; }

    const int srA = tid >> 2;
    const int lchA = ((lane & 3) - (srA >> 1)) & 3;
    const ushort* AgB = A + (size_t)(m0 + srA) * K + lchA * 8;
    const int srB = w * 32 + (lane >> 2);
    const int lchB = ((lane & 3) - (srB >> 1)) & 3;
    const ushort* BgB0 = wt + (size_t)(n0 + srB) * K + lchB * 8;
    const ushort* BgB1 = BgB0 + (size_t)16 * K;
    const int aoff = tid * 8;
    const int boff = srB * 32 + (lane & 3) * 8;
    const int pc = (quad + (ln >> 1)) & 3;

    g2lds16(AgB, &As[0][aoff]);
    g2lds16(BgB0, &Bs[0][boff]);
    g2lds16(BgB1, &Bs[0][boff + 512]);

    f32x4 acc[2][4] = {};
    int buf = 0;
    for (int k0 = 0; k0 < K; k0 += 32) {
        __syncthreads();
        if (k0 + 32 < K) {
            g2lds16(AgB + k0 + 32, &As[buf ^ 1][aoff]);
            g2lds16(BgB0 + k0 + 32, &Bs[buf ^ 1][boff]);
            g2lds16(BgB1 + k0 + 32, &Bs[buf ^ 1][boff + 512]);
        }
        bf16x8 af[2], bfr[4];
        #pragma unroll
        for (int mi = 0; mi < 2; ++mi)
            af[mi] = *(const bf16x8*)&As[buf][(wm * 32 + mi * 16 + ln) * 32 + pc * 8];
        #pragma unroll
        for (int ni = 0; ni < 4; ++ni)
            bfr[ni] = *(const bf16x8*)&Bs[buf][(wn * 64 + ni * 16 + ln) * 32 + pc * 8];
        #pragma unroll
        for (int mi = 0; mi < 2; ++mi)
            #pragma unroll
            for (int ni = 0; ni < 4; ++ni)
                acc[mi][ni] = __builtin_amdgcn_mfma_f32_16x16x32_bf16(
                    af[mi], bfr[ni], acc[mi][ni], 0, 0, 0);
        buf ^= 1;
    }

    const int head = blockIdx.y * 2 + wn;
    const int b = m0 >> 11;
    const size_t bh = (size_t)b * H_ + head;
    if (z == 0) {
        #pragma unroll
        for (int mi = 0; mi < 2; ++mi) {
            const int s = (m0 & (S_ - 1)) + wm * 32 + mi * 16 + quad * 4;
            // t-permutation: group (s>>2)&3 == quad -> slot [0,2,3,1]
            const int sp = (s & ~15) | ((((0x1320u >> (quad * 4)) & 0xFu)) << 2);
            #pragma unroll
            for (int ni = 0; ni < 4; ++ni) {
                const int d = ni * 16 + ln;
                ushort4 o;
                o.x = f2bf(acc[mi][ni][0]); o.y = f2bf(acc[mi][ni][1]);
                o.z = f2bf(acc[mi][ni][2]); o.w = f2bf(acc[mi][ni][3]);
                *(ushort4*)(co + (bh * 64 + d) * S_ + sp) = o;
            }
        }
        float a4[4];
        #pragma unroll
        for (int ni = 0; ni < 4; ++ni) a4[ni] = ar[ni * 16 + ln];
        #pragma unroll
        for (int mi = 0; mi < 2; ++mi) {
            const int s = (m0 & (S_ - 1)) + wm * 32 + mi * 16 + quad * 4;
            #pragma unroll
            for (int r = 0; r < 4; ++r) {
                float v = 0.f;
                #pragma unroll
                for (int ni = 0; ni < 4; ++ni)
                    v += leaky(acc[mi][ni][r]) * a4[ni];
                #pragma unroll
                for (int off = 8; off; off >>= 1) v += __shfl_xor(v, off, 16);
                if (ln == 0) sred[bh * S_ + s + r] = v * scl;
            }
        }
    } else {
        #pragma unroll
        for (int mi = 0; mi < 2; ++mi) {
            const int s = (m0 & (S_ - 1)) + wm * 32 + mi * 16 + quad * 4;
            #pragma unroll
            for (int ni = 0; ni < 4; ++ni) {
                const int d = ni * 16 + ln;
                #pragma unroll
                for (int r = 0; r < 4; ++r)
                    co[(bh * S_ + s + r) * 64 + d] = f2bf(acc[mi][ni][r] * scl);
            }
        }
    }
}

// ---------------------------------------------------------------------------
// Flash attention, 32x32x16 bf16 MFMA, swapped QK^T, in-register P.
// Round 8: R7's t-split structure with the RULE-#20 FIX — the epilogue's
// ctx[qt][th]/ctx[qt][1-th] runtime indexing sent the whole f32x16 ctx[2][2]
// to scratch (VGPR 160->120, WRITE_SIZE 8->104 MB, every PV accumulation
// round-tripping local memory). Epilogue is now branched on wave-uniform th
// with fully static ctx indices.
// ---------------------------------------------------------------------------
#define WAITV(N) asm volatile("s_waitcnt vmcnt(" #N ")" ::: "memory")
#define BARR()   __builtin_amdgcn_s_barrier()

__global__ __launch_bounds__(256, 1) void attn_mfma(
    const ushort* __restrict__ frT, const ushort* __restrict__ rk,
    const ushort* __restrict__ rq, const float* __restrict__ sr,
    ushort* __restrict__ hsa)
{
    __shared__ ushort SMEM[16384];     // 32 KB: RQ[2] @0, FT[2] @8192 (ushorts)
    __shared__ float  LS[4][2][64];    // lsum exchange, 2 KB
    ushort* RQp = SMEM;
    ushort* FTp = SMEM + 8192;

    const int tid = threadIdx.x;
    const int w = tid >> 6;            // wave 0..3
    const int qg = w >> 1;             // q-group
    const int th = w & 1;              // t-half
    const int lane = tid & 63;
    const int lq = lane & 31;
    const int hi = lane >> 5;

    // bijective XCD swizzle over 512 blocks
    const int flat = blockIdx.x + 16 * (blockIdx.y + 8 * blockIdx.z);
    const int wid = (flat & 7) * 64 + (flat >> 3);
    const int q0 = (wid & 15) * 128;
    const int h = (wid >> 4) & 7;
    const int b = wid >> 7;
    const size_t bh = (size_t)b * H_ + h;
    const int qb = q0 + 64 * qg;       // wave's 64 q

    // rk B-frags: col q = qb + 32*qt + lq, k = ks*16 + hi*8
    bf16x8 bq[2][4];
    #pragma unroll
    for (int qt = 0; qt < 2; ++qt) {
        const ushort* p = rk + ((bh * S_ + qb + 32 * qt + lq) << 6) + hi * 8;
        #pragma unroll
        for (int ks = 0; ks < 4; ++ks)
            bq[qt][ks] = *(const bf16x8*)(p + ks * 16);
    }

    const ushort* rq_g = rq + (bh * S_ << 6);
    const ushort* ft_g = frT + (size_t)bh * 64 * S_;
    const float* srp = sr + bh * S_;

    // staging (256 thr): rows rr = 32j + (tid>>3), granule pg = tid&7;
    // 2 rows x 2 arrays = 4 g2lds16/thread. Per-wave dest is lane-linear.
    const int srow = tid >> 3;         // 0..31
    const int pg = tid & 7;
    const int oS = (pg - (srow & 7)) & 7;

    #define STAGE(BUF, t0)                                                    \
        { _Pragma("unroll")                                                   \
          for (int j = 0; j < 2; ++j) {                                       \
            const int rr = 32 * j + srow;                                     \
            g2lds16(rq_g + ((size_t)((t0) + rr) << 6) + oS * 8,               \
                    RQp + (BUF) * 4096 + rr * 64 + pg * 8);                   \
            g2lds16(ft_g + (size_t)rr * S_ + (t0) + oS * 8,                   \
                    FTp + (BUF) * 4096 + rr * 64 + pg * 8);                   \
          } }

    f32x16 ctx[2][2] = {};
    float lsum[2] = {0.f, 0.f};

    #define COMPUTE(BI, TC)                                                    \
    {                                                                          \
        bf16x8 af[4];                                                          \
        _Pragma("unroll")                                                      \
        for (int ks = 0; ks < 4; ++ks)                                         \
            af[ks] = *(const bf16x8*)(RQp + (BI) * 4096 + (th * 32 + lq) * 64  \
                       + ((2 * ks + hi + (lq & 7)) & 7) * 8);                  \
        f32x16 s0 = {}; f32x16 s1 = {};                                        \
        _Pragma("unroll")                                                      \
        for (int ks = 0; ks < 4; ++ks) {                                       \
            s0 = __builtin_amdgcn_mfma_f32_32x32x16_bf16(af[ks], bq[0][ks], s0, 0, 0, 0); \
            s1 = __builtin_amdgcn_mfma_f32_32x32x16_bf16(af[ks], bq[1][ks], s1, 0, 0, 0); \
        }                                                                      \
        float sva[16];                                                         \
        _Pragma("unroll")                                                      \
        for (int jj = 0; jj < 4; ++jj) {                                       \
            const float4 v = *(const float4*)(srp + (TC) + th * 32 + jj * 8 + hi * 4); \
            sva[jj * 4 + 0] = v.x; sva[jj * 4 + 1] = v.y;                      \
            sva[jj * 4 + 2] = v.z; sva[jj * 4 + 3] = v.w;                      \
        }                                                                      \
        uint4 paw[2][2];                                                       \
        _Pragma("unroll")                                                      \
        for (int qt = 0; qt < 2; ++qt) {                                       \
            float p[16];                                                       \
            _Pragma("unroll")                                                  \
            for (int r = 0; r < 16; ++r)                                       \
                p[r] = __builtin_amdgcn_exp2f((qt ? s1[r] : s0[r]) + sva[r]);  \
            float ls = 0.f;                                                    \
            _Pragma("unroll")                                                  \
            for (int r = 0; r < 16; ++r) ls += p[r];                           \
            lsum[qt] += ls;                                                    \
            _Pragma("unroll")                                                  \
            for (int c = 0; c < 2; ++c) {                                      \
                const int e = 8 * c;                                           \
                unsigned c01 = cvtpk(p[e + 0], p[e + 1]);                      \
                unsigned c23 = cvtpk(p[e + 2], p[e + 3]);                      \
                unsigned c45 = cvtpk(p[e + 4], p[e + 5]);                      \
                unsigned c67 = cvtpk(p[e + 6], p[e + 7]);                      \
                plane32swap(c45, c67);                                         \
                paw[qt][c] = make_uint4(c01, c23, c67, c45);                   \
            }                                                                  \
        }                                                                      \
        _Pragma("unroll")                                                      \
        for (int c = 0; c < 2; ++c) {                                          \
            _Pragma("unroll")                                                  \
            for (int dt = 0; dt < 2; ++dt) {                                   \
                const bf16x8 fv = *(const bf16x8*)(FTp + (BI) * 4096           \
                    + (dt * 32 + lq) * 64                                      \
                    + ((4 * th + 2 * c + hi + (lq & 7)) & 7) * 8);             \
                ctx[0][dt] = __builtin_amdgcn_mfma_f32_32x32x16_bf16(          \
                    __builtin_bit_cast(bf16x8, paw[0][c]), fv, ctx[0][dt], 0, 0, 0); \
                ctx[1][dt] = __builtin_amdgcn_mfma_f32_32x32x16_bf16(          \
                    __builtin_bit_cast(bf16x8, paw[1][c]), fv, ctx[1][dt], 0, 0, 0); \
            }                                                                  \
        }                                                                      \
    }

    // prologue
    STAGE(0, 0)
    // 32 tiles: 15 x 2 + tail 2
    for (int it = 0; it < 15; ++it) {
        const int t0 = it * 128;
        WAITV(0); BARR();
        STAGE(1, t0 + 64)
        COMPUTE(0, t0)
        WAITV(0); BARR();
        STAGE(0, t0 + 128)
        COMPUTE(1, t0 + 64)
    }
    WAITV(0); BARR();
    STAGE(1, 1984)
    COMPUTE(0, 1920)
    WAITV(0); BARR();
    COMPUTE(1, 1984)

    // ---- epilogue: combine t-split partials across partner waves ----
    // Branched on wave-uniform th so ALL ctx indices are compile-time
    // constants (rule #20: runtime-indexed ext_vector arrays go to scratch).
    BARR();   // all compute reads of SMEM done; safe to reuse as CX
    float* CX = (float*)SMEM;                 // 8192 floats = 32 KB
    float* CXw = CX + w * 2048;

    #define EPILOGUE(OWN, OTH)                                                \
    {                                                                         \
        _Pragma("unroll")                                                     \
        for (int qt = 0; qt < 2; ++qt)                                        \
            _Pragma("unroll")                                                 \
            for (int r = 0; r < 16; ++r)                                      \
                CXw[(qt * 16 + r) * 64 + lane] = ctx[qt][OTH][r];             \
        LS[w][0][lane] = lsum[0];                                             \
        LS[w][1][lane] = lsum[1];                                             \
        BARR();                                                               \
        const float* CXp = CX + (w ^ 1) * 2048;                               \
        _Pragma("unroll")                                                     \
        for (int qt = 0; qt < 2; ++qt) {                                      \
            float lt = lsum[qt] + LS[w ^ 1][qt][lane];                        \
            const float l = lt + __shfl_xor(lt, 32, 64);                      \
            const float inv = 1.f / l;                                        \
            _Pragma("unroll")                                                 \
            for (int r = 0; r < 16; ++r) {                                    \
                const float cv = ctx[qt][OWN][r] + CXp[(qt * 16 + r) * 64 + lane]; \
                const int rho = (r & 3) + 8 * (r >> 2) + 4 * hi;              \
                const float fi = __shfl(inv, rho, 64);                        \
                const int q = qb + 32 * qt + rho;                             \
                hsa[(size_t)(b * S_ + q) * D_ + h * 64 + (OWN) * 32 + lq] = f2bf(cv * fi); \
            }                                                                 \
        }                                                                     \
    }

    if (th == 0) EPILOGUE(0, 1)
    else         EPILOGUE(1, 0)
}

// ---------------------------------------------------------------------------
// final projection GEMM (fp32 out), double-buffered
// ---------------------------------------------------------------------------
__global__ __launch_bounds__(256) void gemm_out(
    const ushort* __restrict__ A, const ushort* __restrict__ WT,
    float* __restrict__ C)
{
    __shared__ ushort As[2][64 * 32];
    __shared__ ushort Bs[2][128 * 32];

    const int tid = threadIdx.x;
    const int lane = tid & 63, w = tid >> 6;
    const int ln = lane & 15, quad = lane >> 4;
    const int wm = w >> 1, wn = w & 1;
    const int m0 = blockIdx.x * 64, n0 = blockIdx.y * 128;
    const int K = 512;

    const int srA = tid >> 2;
    const int lchA = ((lane & 3) - (srA >> 1)) & 3;
    const ushort* AgB = A + (size_t)(m0 + srA) * K + lchA * 8;
    const int srB = w * 32 + (lane >> 2);
    const int lchB = ((lane & 3) - (srB >> 1)) & 3;
    const ushort* BgB0 = WT + (size_t)(n0 + srB) * K + lchB * 8;
    const ushort* BgB1 = BgB0 + (size_t)16 * K;
    const int aoff = tid * 8;
    const int boff = srB * 32 + (lane & 3) * 8;
    const int pc = (quad + (ln >> 1)) & 3;

    g2lds16(AgB, &As[0][aoff]);
    g2lds16(BgB0, &Bs[0][boff]);
    g2lds16(BgB1, &Bs[0][boff + 512]);

    f32x4 acc[2][4] = {};
    int buf = 0;
    for (int k0 = 0; k0 < K; k0 += 32) {
        __syncthreads();
        if (k0 + 32 < K) {
            g2lds16(AgB + k0 + 32, &As[buf ^ 1][aoff]);
            g2lds16(BgB0 + k0 + 32, &Bs[buf ^ 1][boff]);
            g2lds16(BgB1 + k0 + 32, &Bs[buf ^ 1][boff + 512]);
        }
        bf16x8 af[2], bfr[4];
        #pragma unroll
        for (int mi = 0; mi < 2; ++mi)
            af[mi] = *(const bf16x8*)&As[buf][(wm * 32 + mi * 16 + ln) * 32 + pc * 8];
        #pragma unroll
        for (int ni = 0; ni < 4; ++ni)
            bfr[ni] = *(const bf16x8*)&Bs[buf][(wn * 64 + ni * 16 + ln) * 32 + pc * 8];
        #pragma unroll
        for (int mi = 0; mi < 2; ++mi)
            #pragma unroll
            for (int ni = 0; ni < 4; ++ni)
                acc[mi][ni] = __builtin_amdgcn_mfma_f32_16x16x32_bf16(
                    af[mi], bfr[ni], acc[mi][ni], 0, 0, 0);
        buf ^= 1;
    }

    #pragma unroll
    for (int mi = 0; mi < 2; ++mi) {
        const int row = m0 + wm * 32 + mi * 16 + quad * 4;
        #pragma unroll
        for (int ni = 0; ni < 4; ++ni) {
            const int col = n0 + wn * 64 + ni * 16 + ln;
            #pragma unroll
            for (int r = 0; r < 4; ++r)
                C[(size_t)(row + r) * 512 + col] = acc[mi][ni][r];
        }
    }
}

// ---------------------------------------------------------------------------
// LayerNorm(h + fh) * g + b
// ---------------------------------------------------------------------------
__global__ __launch_bounds__(256) void ln_kernel(
    const float* __restrict__ h, const float* __restrict__ fh,
    const float* __restrict__ g, const float* __restrict__ bb,
    float* __restrict__ out)
{
    const int row = blockIdx.x, tid = threadIdx.x;
    const float* hp = h + (size_t)row * 512;
    const float* fp = fh + (size_t)row * 512;
    const float x0 = hp[tid] + fp[tid];
    const float x1 = hp[tid + 256] + fp[tid + 256];
    __shared__ float red[4];

    float s = x0 + x1;
    #pragma unroll
    for (int off = 32; off; off >>= 1) s += __shfl_xor(s, off, 64);
    if ((tid & 63) == 0) red[tid >> 6] = s;
    __syncthreads();
    const float mu = (red[0] + red[1] + red[2] + red[3]) * (1.f / 512.f);

    const float d0 = x0 - mu, d1 = x1 - mu;
    float v = d0 * d0 + d1 * d1;
    #pragma unroll
    for (int off = 32; off; off >>= 1) v += __shfl_xor(v, off, 64);
    __syncthreads();
    if ((tid & 63) == 0) red[tid >> 6] = v;
    __syncthreads();
    const float var = (red[0] + red[1] + red[2] + red[3]) * (1.f / 512.f);
    const float inv = rsqrtf(var + LN_EPS);

    out[(size_t)row * 512 + tid] = d0 * inv * g[tid] + bb[tid];
    out[(size_t)row * 512 + tid + 256] = d1 * inv * g[tid + 256] + bb[tid + 256];
}

// ---------------------------------------------------------------------------
extern "C" void kernel_launch(void* const* d_in, const int* in_sizes, int n_in,
                              void* d_out, int out_size, void* d_ws, size_t ws_size,
                              hipStream_t stream)
{
    const float* h   = (const float*)d_in[0];
    const float* rh  = (const float*)d_in[1];
    // d_in[2] = Wl, d_in[4] = al : unused — sl cancels in softmax
    const float* Wr  = (const float*)d_in[3];
    const float* ar  = (const float*)d_in[5];
    const float* Wrs = (const float*)d_in[6];
    const float* Wrt = (const float*)d_in[7];
    const float* Wf  = (const float*)d_in[8];
    const float* lng = (const float*)d_in[9];
    const float* lnb = (const float*)d_in[10];
    float* out = (float*)d_out;
    char* wsb  = (char*)d_ws;

    const size_t MB = (size_t)1 << 20;
    ushort* hb   = (ushort*)(wsb);               //  8 MB
    ushort* rhb  = (ushort*)(wsb + 8 * MB);      //  1 MB
    ushort* WrT  = (ushort*)(wsb + 9 * MB);      // .5 MB
    ushort* WfT  = (ushort*)(wsb + 9 * MB + 512 * 1024);
    ushort* WrsT = (ushort*)(wsb + 10 * MB);     // 64 KB
    ushort* WrtT = (ushort*)(wsb + 10 * MB + 64 * 1024);
    ushort* frT  = (ushort*)(wsb + 11 * MB);     //  8 MB  [B,H,64,S] (t-permuted)
    ushort* rkw  = (ushort*)(wsb + 19 * MB);     //  8 MB  [B,H,S,64]
    ushort* rqw  = (ushort*)(wsb + 27 * MB);     //  8 MB  [B,H,S,64]
    float*  sr   = (float*) (wsb + 35 * MB);     // .25MB  [B,H,S]
    ushort* hsab = (ushort*)(wsb + 36 * MB);     //  8 MB  [B,S,512] bf16
    float*  fh   = (float*) (wsb + 44 * MB);     // 16 MB  [B,S,512] f32

    dim3 blk(256);
    prep<<<dim3(4752), blk, 0, stream>>>(h, rh, Wr, Wf, Wrs, Wrt,
                                         hb, rhb, WrT, WfT, WrsT, WrtT);
    proj<<<dim3(128, 4, 3), blk, 0, stream>>>(hb, rhb, WrT, WrsT, WrtT,
                                              frT, rkw, rqw, sr, ar);
    // attention: 4 waves (2 q-groups x 2 t-halves) per 256-thread block
    attn_mfma<<<dim3(S_ / 128, H_, B_), blk, 0, stream>>>(frT, rkw, rqw, sr, hsab);
    gemm_out<<<dim3(128, 4), blk, 0, stream>>>(hsab, WfT, fh);
    ln_kernel<<<dim3(B_ * S_), blk, 0, stream>>>(h, fh, lng, lnb, out);
}